// Round 17
// baseline (98.814 us; speedup 1.0000x reference)
//
#include <hip/hip_runtime.h>

#define BB 16
#define CC 80
#define HWs 16384           // H*W
#define KK 100
#define NBIN 2048           // histogram bins = okey(logit) >> 21
#define NBLK (BB * CC * 2)  // 2560 half-plane blocks
#define NSLOT 160           // half-plane slots per batch = CC*2
#define BCAP 1152           // records per half-plane slot (mean ~910, +27%)
#define SBCAP 64            // survivors per half-plane slot (mean ~4)

// ws layout (bytes)
#define OFF_BHIST 0                          // 16*2048*4 = 131072
#define OFF_CUT   131072                     // 64
#define OFF_PBCNT 131136                     // 2560*4 = 10240
#define OFF_PSCNT 141376                     // 2560*4 = 10240
#define OFF_SURV  151616                     // 2560*64*4 = 655360
#define OFF_REC   806976                     // 2560*1152*4 = 11796480 (end ~12.6MB)

__device__ __forceinline__ unsigned okey(float f) {
    unsigned u = __float_as_uint(f);
    return (u & 0x80000000u) ? ~u : (u | 0x80000000u);
}

// zero bhist (128 KB)
__global__ __launch_bounds__(256) void zero_hist_kernel(int4* __restrict__ bhist) {
    int i = blockIdx.x * 256 + threadIdx.x;          // 8192 int4 total
    if (i < BB * NBIN / 4) bhist[i] = make_int4(0, 0, 0, 0);
}

// ===== verified R16 pipeline (byte-identical logic) =====

__global__ __launch_bounds__(256) void nms_kernel(const float* __restrict__ hm,
                                                  unsigned* __restrict__ rec,
                                                  int* __restrict__ pbcnt,
                                                  int* __restrict__ bhist) {
    __shared__ int hist[NBIN];             // 8 KB
    __shared__ unsigned sbuf[BCAP];        // 4.5 KB
    __shared__ int s_n;
    const int blk = blockIdx.x;            // plane*2 + half
    const int plane = blk >> 1;
    const int half = blk & 1;
    const int b = plane / CC;
    const int c = plane - b * CC;
    const int t = threadIdx.x;
    const int sx = t & 31;                 // 4-wide column strip
    const int x0 = sx << 2;
    const int g = t >> 5;                  // 8 row-groups
    const int yA = (half << 6) + (g << 2); // rows yA..yA+3
    const int yB = yA + 32;                // rows yB..yB+3
    const float4* __restrict__ src4 =
        reinterpret_cast<const float4*>(hm + (size_t)plane * HWs);

    for (int i = t; i < NBIN; i += 256) hist[i] = 0;
    if (t == 0) s_n = 0;
    __syncthreads();

    float4 wa[6], wb[6];
#pragma unroll
    for (int i = 0; i < 6; ++i) {
        int ra = yA - 1 + i; ra = ra < 0 ? 0 : (ra > 127 ? 127 : ra);
        int rb = yB - 1 + i; rb = rb < 0 ? 0 : (rb > 127 ? 127 : rb);
        wa[i] = src4[(ra << 5) + sx];
        wb[i] = src4[(rb << 5) + sx];
    }
    __builtin_amdgcn_sched_barrier(0);

    auto hmax3 = [&](const float4& a) -> float4 {
        float vm1 = __shfl_up(a.w, 1, 32);
        float vp4 = __shfl_down(a.x, 1, 32);
        if (sx == 0) vm1 = a.x;
        if (sx == 31) vp4 = a.w;
        float4 h;
        h.x = fmaxf(fmaxf(vm1, a.x), a.y);
        h.y = fmaxf(fmaxf(a.x, a.y), a.z);
        h.z = fmaxf(fmaxf(a.y, a.z), a.w);
        h.w = fmaxf(fmaxf(a.z, a.w), vp4);
        return h;
    };

    auto process = [&](const float4* w, int y0) {
        float4 hm1 = hmax3(w[0]);
        float4 h0  = hmax3(w[1]);
#pragma unroll
        for (int r = 0; r < 4; ++r) {
            float4 hp1 = hmax3(w[r + 2]);
            float vv[4] = { w[r + 1].x, w[r + 1].y, w[r + 1].z, w[r + 1].w };
            float mm[4] = { fmaxf(fmaxf(hm1.x, h0.x), hp1.x),
                            fmaxf(fmaxf(hm1.y, h0.y), hp1.y),
                            fmaxf(fmaxf(hm1.z, h0.z), hp1.z),
                            fmaxf(fmaxf(hm1.w, h0.w), hp1.w) };
#pragma unroll
            for (int j = 0; j < 4; ++j) {
                if (vv[j] >= mm[j]) {
                    int sl = atomicAdd(&s_n, 1);
                    unsigned bin = okey(vv[j]) >> 21;
                    unsigned idx = ((unsigned)c << 14)
                                 | ((unsigned)(y0 + r) << 7) | (unsigned)(x0 + j);
                    if (sl < BCAP) sbuf[sl] = (bin << 21) | idx;
                }
            }
            hm1 = h0; h0 = hp1;
        }
    };
    process(wa, yA);
    process(wb, yB);

    __syncthreads();
    int n = s_n; if (n > BCAP) n = BCAP;

    for (int i = t; i < n; i += 256) atomicAdd(&hist[sbuf[i] >> 21], 1);
    __syncthreads();
    for (int i = t; i < NBIN; i += 256) {
        int hv = hist[i];
        if (hv) atomicAdd(&bhist[b * NBIN + i], hv);
    }
    unsigned* __restrict__ rb = rec + (size_t)blk * BCAP;
    for (int i = t; i < n; i += 256) rb[i] = sbuf[i];
    if (t == 0) pbcnt[blk] = n;
}

__global__ __launch_bounds__(256) void cut_kernel(const int* __restrict__ bhist,
                                                  int* __restrict__ cut) {
    __shared__ int csum[256];
    __shared__ int s_cut;
    const int b = blockIdx.x;
    const int t = threadIdx.x;

    int h[8]; int chunk = 0;
#pragma unroll
    for (int j = 0; j < 8; ++j) {
        h[j] = bhist[b * NBIN + (t << 3) + j];
        chunk += h[j];
    }
    csum[t] = chunk;
    if (t == 0) s_cut = 0;
    __syncthreads();
    for (int off = 1; off < 256; off <<= 1) {
        int v = (t + off < 256) ? csum[t + off] : 0;
        __syncthreads();
        csum[t] += v;
        __syncthreads();
    }
    if (csum[0] > KK) {
        int running = (t < 255) ? csum[t + 1] : 0;
        if (csum[t] >= KK && running < KK) {
            for (int j = 7; j >= 0; --j) {
                running += h[j];
                if (running >= KK) { s_cut = (t << 3) + j; break; }
            }
        }
    }
    __syncthreads();
    if (t == 0) cut[b] = s_cut;
}

__global__ __launch_bounds__(256) void filter_kernel(const unsigned* __restrict__ rec,
                                                     const int* __restrict__ pbcnt,
                                                     const int* __restrict__ cut,
                                                     unsigned* __restrict__ surv,
                                                     int* __restrict__ pscnt) {
    __shared__ int s_n;
    const int blk = blockIdx.x;
    const int b = blk / NSLOT;
    const int t = threadIdx.x;
    if (t == 0) s_n = 0;
    __syncthreads();

    int n = pbcnt[blk]; if (n > BCAP) n = BCAP;
    const unsigned cutb = (unsigned)cut[b];
    const unsigned* __restrict__ rb = rec + (size_t)blk * BCAP;
    unsigned* __restrict__ sb = surv + (size_t)blk * SBCAP;
    for (int i = t; i < n; i += 256) {
        unsigned rv = rb[i];
        if ((rv >> 21) >= cutb) {
            int sl = atomicAdd(&s_n, 1);
            if (sl < SBCAP) sb[sl] = rv & 0x1FFFFFu;
        }
    }
    __syncthreads();
    if (t == 0) pscnt[blk] = s_n > SBCAP ? SBCAP : s_n;
}

__global__ __launch_bounds__(256) void topk_kernel(const unsigned* __restrict__ surv,
                                                   const int* __restrict__ pscnt,
                                                   const float* __restrict__ hm,
                                                   const float* __restrict__ bbox,
                                                   const float* __restrict__ offs,
                                                   const int* __restrict__ image_id,
                                                   float* __restrict__ out) {
    __shared__ int lcnt[NSLOT];
    __shared__ unsigned uidx[2048];
    __shared__ unsigned long long list[2048];
    __shared__ int s_n;
    const int b = blockIdx.x;
    const int t = threadIdx.x;
    const float* __restrict__ hb = hm + (size_t)b * CC * HWs;

    if (t < NSLOT) lcnt[t] = pscnt[b * NSLOT + t];
    if (t == 0) s_n = 0;
    __syncthreads();

    for (int s = t; s < NSLOT; s += 256) {
        int cs = lcnt[s]; if (cs > SBCAP) cs = SBCAP;
        if (cs) {
            int base = atomicAdd(&s_n, cs);
            const unsigned* __restrict__ sb = surv + ((size_t)b * NSLOT + s) * SBCAP;
            for (int k = 0; k < cs; ++k)
                if (base + k < 2048) uidx[base + k] = sb[k];
        }
    }
    __syncthreads();
    int n = s_n; if (n > 2048) n = 2048;

    for (int i = t; i < n; i += 256) {
        unsigned idx = uidx[i];
        float lv = hb[idx];
        float s = 1.0f / (1.0f + expf(-lv));
        list[i] = ((unsigned long long)__float_as_uint(s) << 32) | (unsigned)(~idx);
    }
    int P = 128;
    while (P < n) P <<= 1;
    for (int i = n + t; i < P; i += 256) list[i] = 0ull;
    __syncthreads();

    for (int ksz = 2; ksz <= P; ksz <<= 1) {
        for (int j = ksz >> 1; j > 0; j >>= 1) {
            for (int i = t; i < P; i += 256) {
                int ixj = i ^ j;
                if (ixj > i) {
                    unsigned long long a = list[i], bb2 = list[ixj];
                    bool desc = ((i & ksz) == 0);
                    if (desc ? (a < bb2) : (a > bb2)) { list[i] = bb2; list[ixj] = a; }
                }
            }
            __syncthreads();
        }
    }

    if (t < KK) {
        float s = 0.0f; unsigned idx = 0;
        if (t < n) {
            unsigned long long cv = list[t];
            s = __uint_as_float((unsigned)(cv >> 32));
            idx = ~(unsigned)(cv & 0xFFFFFFFFu) & 0x1FFFFFu;
        }
        unsigned sp = idx & (HWs - 1);
        float cls = (float)(idx >> 14);
        float ysf = (float)(sp >> 7);
        float xsf = (float)(sp & 127);
        const float* __restrict__ ob  = offs + (size_t)b * 2 * HWs;
        const float* __restrict__ bbx = bbox + (size_t)b * 2 * HWs;
        float cx = xsf + ob[sp];
        float cy = ysf + ob[HWs + sp];
        float w = bbx[sp];
        float h = bbx[HWs + sp];
        float* row = out + ((size_t)b * KK + t) * 7;
        row[0] = (float)image_id[b];
        row[1] = (cx - w * 0.5f) * 4.0f;
        row[2] = (cy - h * 0.5f) * 4.0f;
        row[3] = (cx + w * 0.5f) * 4.0f;
        row[4] = (cy + h * 0.5f) * 4.0f;
        row[5] = s;
        row[6] = cls;
    }
}

// ===== ABLATION PROBES (timing only; write to rec scratch, which nms fully
// rewrites before filter reads it each replay -> deterministic) =====

// ablA: the EXACT nms load pattern, x2 repeats (column-rotated per repeat to
// defeat CSE), sum-consume. Measures loads-only cost of this access pattern.
__global__ __launch_bounds__(256) void abl_loads_kernel(const float* __restrict__ hm,
                                                        float* __restrict__ dummy) {
    const int blk = blockIdx.x;
    const int plane = blk >> 1;
    const int half = blk & 1;
    const int t = threadIdx.x;
    const int g = t >> 5;
    const int yA = (half << 6) + (g << 2);
    const int yB = yA + 32;
    const float4* __restrict__ src4 =
        reinterpret_cast<const float4*>(hm + (size_t)plane * HWs);

    float acc = 0.0f;
    for (int it = 0; it < 2; ++it) {
        const int sxx = ((t & 31) + it * 13) & 31;
        float4 wa[6], wb[6];
#pragma unroll
        for (int i = 0; i < 6; ++i) {
            int ra = yA - 1 + i; ra = ra < 0 ? 0 : (ra > 127 ? 127 : ra);
            int rb = yB - 1 + i; rb = rb < 0 ? 0 : (rb > 127 ? 127 : rb);
            wa[i] = src4[(ra << 5) + sxx];
            wb[i] = src4[(rb << 5) + sxx];
        }
#pragma unroll
        for (int i = 0; i < 6; ++i)
            acc += wa[i].x + wa[i].y + wa[i].z + wa[i].w
                 + wb[i].x + wb[i].y + wb[i].z + wb[i].w;
    }
    dummy[(size_t)blk * 256 + t] = acc;
}

// ablB: loads + FULL shfl/hmax3 stencil + peak count, x2 repeats.
// No LDS, no atomics, no emit. Measures loads+stencil cost.
__global__ __launch_bounds__(256) void abl_stencil_kernel(const float* __restrict__ hm,
                                                          float* __restrict__ dummy) {
    const int blk = blockIdx.x;
    const int plane = blk >> 1;
    const int half = blk & 1;
    const int t = threadIdx.x;
    const int g = t >> 5;
    const int yA = (half << 6) + (g << 2);
    const int yB = yA + 32;
    const float4* __restrict__ src4 =
        reinterpret_cast<const float4*>(hm + (size_t)plane * HWs);

    int acc = 0;
    for (int it = 0; it < 2; ++it) {
        const int sxx = ((t & 31) + it * 13) & 31;
        auto hmax3 = [&](const float4& a) -> float4 {
            float vm1 = __shfl_up(a.w, 1, 32);
            float vp4 = __shfl_down(a.x, 1, 32);
            if (sxx == 0) vm1 = a.x;
            if (sxx == 31) vp4 = a.w;
            float4 h;
            h.x = fmaxf(fmaxf(vm1, a.x), a.y);
            h.y = fmaxf(fmaxf(a.x, a.y), a.z);
            h.z = fmaxf(fmaxf(a.y, a.z), a.w);
            h.w = fmaxf(fmaxf(a.z, a.w), vp4);
            return h;
        };
        float4 wa[6], wb[6];
#pragma unroll
        for (int i = 0; i < 6; ++i) {
            int ra = yA - 1 + i; ra = ra < 0 ? 0 : (ra > 127 ? 127 : ra);
            int rb = yB - 1 + i; rb = rb < 0 ? 0 : (rb > 127 ? 127 : rb);
            wa[i] = src4[(ra << 5) + sxx];
            wb[i] = src4[(rb << 5) + sxx];
        }
        auto scan = [&](const float4* w) {
            float4 hm1 = hmax3(w[0]);
            float4 h0  = hmax3(w[1]);
#pragma unroll
            for (int r = 0; r < 4; ++r) {
                float4 hp1 = hmax3(w[r + 2]);
                if (w[r + 1].x >= fmaxf(fmaxf(hm1.x, h0.x), hp1.x)) ++acc;
                if (w[r + 1].y >= fmaxf(fmaxf(hm1.y, h0.y), hp1.y)) ++acc;
                if (w[r + 1].z >= fmaxf(fmaxf(hm1.z, h0.z), hp1.z)) ++acc;
                if (w[r + 1].w >= fmaxf(fmaxf(hm1.w, h0.w), hp1.w)) ++acc;
                hm1 = h0; h0 = hp1;
            }
        };
        scan(wa);
        scan(wb);
    }
    dummy[(size_t)blk * 256 + t] = (float)acc;
}

extern "C" void kernel_launch(void* const* d_in, const int* in_sizes, int n_in,
                              void* d_out, int out_size, void* d_ws, size_t ws_size,
                              hipStream_t stream) {
    const float* hm      = (const float*)d_in[0];
    const float* bbox    = (const float*)d_in[1];
    const float* offset  = (const float*)d_in[2];
    const int*   img_id  = (const int*)d_in[3];
    float* out = (float*)d_out;

    char* ws = (char*)d_ws;
    int*      bhist = (int*)(ws + OFF_BHIST);
    int*      cut   = (int*)(ws + OFF_CUT);
    int*      pbcnt = (int*)(ws + OFF_PBCNT);
    int*      pscnt = (int*)(ws + OFF_PSCNT);
    unsigned* surv  = (unsigned*)(ws + OFF_SURV);
    unsigned* rec   = (unsigned*)(ws + OFF_REC);
    float*    dumA  = (float*)(ws + OFF_REC);                 // rec scratch
    float*    dumB  = (float*)(ws + OFF_REC + 2621440);       // rec scratch +2.5MB

    zero_hist_kernel<<<32, 256, 0, stream>>>((int4*)bhist);
    nms_kernel<<<NBLK, 256, 0, stream>>>(hm, rec, pbcnt, bhist);
    cut_kernel<<<BB, 256, 0, stream>>>(bhist, cut);
    filter_kernel<<<NBLK, 256, 0, stream>>>(rec, pbcnt, cut, surv, pscnt);
    topk_kernel<<<BB, 256, 0, stream>>>(surv, pscnt, hm, bbox, offset, img_id, out);
    // --- timing probes (outputs unread; rec is rewritten by nms next replay) ---
    abl_loads_kernel<<<NBLK, 256, 0, stream>>>(hm, dumA);
    abl_stencil_kernel<<<NBLK, 256, 0, stream>>>(hm, dumB);
}

// Round 18
// 82.207 us; speedup vs baseline: 1.2020x; 1.2020x over previous
//
#include <hip/hip_runtime.h>

#define BB 16
#define CC 80
#define HWs 16384           // H*W
#define KK 100
#define NBIN 2048           // histogram bins = okey(logit) >> 21
#define NBLK (BB * CC * 2)  // 2560 half-plane blocks
#define NSLOT 160           // filter slots per batch = CC*2
#define WCAP 288            // records per WAVE slot (mean ~228, +4 sigma)
#define SBCAP 64            // survivors per filter slot (mean ~4)

// ws layout (bytes)
#define OFF_BHIST 0                          // 16*2048*4 = 131072
#define OFF_PWCNT 131072                     // 10240*4 = 40960
#define OFF_PSCNT 172032                     // 2560*4 = 10240
#define OFF_SURV  182272                     // 2560*64*4 = 655360
#define OFF_REC   837632                     // 10240*288*4 = 11796480 (end 12.63MB)

__device__ __forceinline__ unsigned okey(float f) {
    unsigned u = __float_as_uint(f);
    return (u & 0x80000000u) ? ~u : (u | 0x80000000u);
}

// zero bhist (128 KB)
__global__ __launch_bounds__(256) void zero_hist_kernel(int4* __restrict__ bhist) {
    int i = blockIdx.x * 256 + threadIdx.x;          // 8192 int4 total
    if (i < BB * NBIN / 4) bhist[i] = make_int4(0, 0, 0, 0);
}

// One block per half-plane (2560 blocks). ZERO LDS, ZERO atomics, ZERO
// barriers (R17 ablation: loads+stencil <= ~19us; the 30+us residual was
// LDS-atomic emit + in-kernel histogram). Each WAVE owns a private record
// slot; offsets = 6-shfl wave scan + popc(mask&(bit-1)); plain stores only.
__global__ __launch_bounds__(256) void nms_kernel(const float* __restrict__ hm,
                                                  unsigned* __restrict__ rec,
                                                  int* __restrict__ pwcnt) {
    const int blk = blockIdx.x;            // plane*2 + half
    const int plane = blk >> 1;
    const int half = blk & 1;
    const int b = plane / CC;
    const int c = plane - b * CC;
    const int t = threadIdx.x;
    const int lane = t & 63;
    const int wid = t >> 6;
    const int sx = t & 31;                 // 4-wide column strip
    const int x0 = sx << 2;
    const int g = t >> 5;                  // 8 row-groups
    const int yA = (half << 6) + (g << 2); // rows yA..yA+3
    const int yB = yA + 32;                // rows yB..yB+3
    const float4* __restrict__ src4 =
        reinterpret_cast<const float4*>(hm + (size_t)plane * HWs);

    float4 wa[6], wb[6];
#pragma unroll
    for (int i = 0; i < 6; ++i) {
        int ra = yA - 1 + i; ra = ra < 0 ? 0 : (ra > 127 ? 127 : ra);
        int rb = yB - 1 + i; rb = rb < 0 ? 0 : (rb > 127 ? 127 : rb);
        wa[i] = src4[(ra << 5) + sx];
        wb[i] = src4[(rb << 5) + sx];
    }
    __builtin_amdgcn_sched_barrier(0);

    auto hmax3 = [&](const float4& a) -> float4 {
        float vm1 = __shfl_up(a.w, 1, 32);
        float vp4 = __shfl_down(a.x, 1, 32);
        if (sx == 0) vm1 = a.x;            // SAME padding (self-dup neutral)
        if (sx == 31) vp4 = a.w;
        float4 h;
        h.x = fmaxf(fmaxf(vm1, a.x), a.y);
        h.y = fmaxf(fmaxf(a.x, a.y), a.z);
        h.z = fmaxf(fmaxf(a.y, a.z), a.w);
        h.w = fmaxf(fmaxf(a.z, a.w), vp4);
        return h;
    };

    auto mask_of = [&](const float4* w) -> unsigned {
        unsigned pm = 0;
        float4 hm1 = hmax3(w[0]);
        float4 h0  = hmax3(w[1]);
#pragma unroll
        for (int r = 0; r < 4; ++r) {
            float4 hp1 = hmax3(w[r + 2]);
            if (w[r + 1].x >= fmaxf(fmaxf(hm1.x, h0.x), hp1.x)) pm |= 1u << (r * 4 + 0);
            if (w[r + 1].y >= fmaxf(fmaxf(hm1.y, h0.y), hp1.y)) pm |= 1u << (r * 4 + 1);
            if (w[r + 1].z >= fmaxf(fmaxf(hm1.z, h0.z), hp1.z)) pm |= 1u << (r * 4 + 2);
            if (w[r + 1].w >= fmaxf(fmaxf(hm1.w, h0.w), hp1.w)) pm |= 1u << (r * 4 + 3);
            hm1 = h0; h0 = hp1;
        }
        return pm;
    };

    const unsigned pmA = mask_of(wa);
    const unsigned pmB = mask_of(wb);

    // wave inclusive scan of per-thread counts (A then B regions)
    int cntA = __popc(pmA), cntB = __popc(pmB);
    int scA = cntA, scB = cntB;
#pragma unroll
    for (int off = 1; off < 64; off <<= 1) {
        int nA = __shfl_up(scA, off, 64);
        int nB = __shfl_up(scB, off, 64);
        if (lane >= off) { scA += nA; scB += nB; }
    }
    const int totalA = __shfl(scA, 63, 64);
    const int totalB = __shfl(scB, 63, 64);
    const int baseA = scA - cntA;
    const int baseB = totalA + scB - cntB;

    unsigned* __restrict__ wr = rec + (size_t)((blk << 2) + wid) * WCAP;

    auto emit = [&](const float4* w, unsigned pm, int base, int y0) {
#pragma unroll
        for (int r = 0; r < 4; ++r) {
#pragma unroll
            for (int j = 0; j < 4; ++j) {
                unsigned bit = 1u << (r * 4 + j);
                if (pm & bit) {
                    float lv = (j == 0) ? w[r + 1].x : (j == 1) ? w[r + 1].y
                             : (j == 2) ? w[r + 1].z : w[r + 1].w;
                    int slot = base + __popc(pm & (bit - 1));
                    unsigned idx = ((unsigned)c << 14)
                                 | ((unsigned)(y0 + r) << 7) | (unsigned)(x0 + j);
                    if (slot < WCAP)
                        wr[slot] = ((okey(lv) >> 21) << 21) | idx;
                }
            }
        }
    };
    emit(wa, pmA, baseA, yA);
    emit(wb, pmB, baseB, yB);

    if (lane == 63) {
        int tot = totalA + totalB;
        pwcnt[(blk << 2) + wid] = tot > WCAP ? WCAP : tot;
    }
}

// 160 blocks (10 per batch): build per-batch histogram from records.
// Each block: 64 wave-slots of one batch -> LDS hist -> global atomic flush.
__global__ __launch_bounds__(256) void hist_kernel(const unsigned* __restrict__ rec,
                                                   const int* __restrict__ pwcnt,
                                                   int* __restrict__ bhist) {
    __shared__ int hist[NBIN];             // 8 KB
    __shared__ int lcnt[64];
    const int bx = blockIdx.x;             // b*10 + p
    const int b = bx / 10;
    const int p = bx - b * 10;
    const int slot0 = b * 640 + p * 64;
    const int t = threadIdx.x;

    for (int i = t; i < NBIN; i += 256) hist[i] = 0;
    if (t < 64) {
        int n = pwcnt[slot0 + t];
        lcnt[t] = n > WCAP ? WCAP : n;
    }
    __syncthreads();

    for (int s = 0; s < 64; ++s) {
        int n = lcnt[s];
        const unsigned* __restrict__ rb = rec + (size_t)(slot0 + s) * WCAP;
        for (int i = t; i < n; i += 256) atomicAdd(&hist[rb[i] >> 21], 1);
    }
    __syncthreads();
    for (int i = t; i < NBIN; i += 256) {
        int hv = hist[i];
        if (hv) atomicAdd(&bhist[b * NBIN + i], hv);   // fire-and-forget
    }
}

// One block per 4 wave-slots (2560 blocks): inline cut (verified R12 logic:
// largest bin with suffix >= K, superset of exact top-100 incl. ties), then
// filter the 4 wave-slots -> deterministic survivor slot.
__global__ __launch_bounds__(256) void filter_kernel(const unsigned* __restrict__ rec,
                                                     const int* __restrict__ pwcnt,
                                                     const int* __restrict__ bhist,
                                                     unsigned* __restrict__ surv,
                                                     int* __restrict__ pscnt) {
    __shared__ int csum[256];
    __shared__ int s_cut, s_n;
    const int blk = blockIdx.x;            // b*NSLOT + slot
    const int b = blk / NSLOT;
    const int t = threadIdx.x;

    int h[8]; int chunk = 0;
#pragma unroll
    for (int j = 0; j < 8; ++j) {
        h[j] = bhist[b * NBIN + (t << 3) + j];
        chunk += h[j];
    }
    csum[t] = chunk;
    if (t == 0) { s_cut = 0; s_n = 0; }
    __syncthreads();
    for (int off = 1; off < 256; off <<= 1) {
        int v = (t + off < 256) ? csum[t + off] : 0;
        __syncthreads();
        csum[t] += v;
        __syncthreads();
    }
    if (csum[0] > KK) {
        int running = (t < 255) ? csum[t + 1] : 0;
        if (csum[t] >= KK && running < KK) {   // exactly one thread
            for (int j = 7; j >= 0; --j) {
                running += h[j];
                if (running >= KK) { s_cut = (t << 3) + j; break; }
            }
        }
    }
    __syncthreads();
    const unsigned cutb = (unsigned)s_cut;

    unsigned* __restrict__ sb = surv + (size_t)blk * SBCAP;
#pragma unroll
    for (int k = 0; k < 4; ++k) {
        int ws = (blk << 2) + k;
        int n = pwcnt[ws]; if (n > WCAP) n = WCAP;
        const unsigned* __restrict__ rb = rec + (size_t)ws * WCAP;
        for (int i = t; i < n; i += 256) {
            unsigned rv = rb[i];
            if ((rv >> 21) >= cutb) {
                int sl = atomicAdd(&s_n, 1);   // LDS atomic: rare
                if (sl < SBCAP) sb[sl] = rv & 0x1FFFFFu;
            }
        }
    }
    __syncthreads();
    if (t == 0) pscnt[blk] = s_n > SBCAP ? SBCAP : s_n;
}

// One block per batch: gather survivors, exact logit -> sigmoid, sort by
// (sigmoid_bits desc, idx asc) == lax.top_k tie semantics, gather + emit.
__global__ __launch_bounds__(256) void topk_kernel(const unsigned* __restrict__ surv,
                                                   const int* __restrict__ pscnt,
                                                   const float* __restrict__ hm,
                                                   const float* __restrict__ bbox,
                                                   const float* __restrict__ offs,
                                                   const int* __restrict__ image_id,
                                                   float* __restrict__ out) {
    __shared__ int lcnt[NSLOT];
    __shared__ unsigned uidx[2048];            // 8 KB
    __shared__ unsigned long long list[2048];  // 16 KB
    __shared__ int s_n;
    const int b = blockIdx.x;
    const int t = threadIdx.x;
    const float* __restrict__ hb = hm + (size_t)b * CC * HWs;

    if (t < NSLOT) lcnt[t] = pscnt[b * NSLOT + t];
    if (t == 0) s_n = 0;
    __syncthreads();

    for (int s = t; s < NSLOT; s += 256) {
        int cs = lcnt[s]; if (cs > SBCAP) cs = SBCAP;
        if (cs) {
            int base = atomicAdd(&s_n, cs);
            const unsigned* __restrict__ sb = surv + ((size_t)b * NSLOT + s) * SBCAP;
            for (int k = 0; k < cs; ++k)
                if (base + k < 2048) uidx[base + k] = sb[k];
        }
    }
    __syncthreads();
    int n = s_n; if (n > 2048) n = 2048;

    for (int i = t; i < n; i += 256) {
        unsigned idx = uidx[i];
        float lv = hb[idx];
        float s = 1.0f / (1.0f + expf(-lv));
        list[i] = ((unsigned long long)__float_as_uint(s) << 32) | (unsigned)(~idx);
    }
    int P = 128;
    while (P < n) P <<= 1;
    for (int i = n + t; i < P; i += 256) list[i] = 0ull;
    __syncthreads();

    for (int ksz = 2; ksz <= P; ksz <<= 1) {
        for (int j = ksz >> 1; j > 0; j >>= 1) {
            for (int i = t; i < P; i += 256) {
                int ixj = i ^ j;
                if (ixj > i) {
                    unsigned long long a = list[i], bb2 = list[ixj];
                    bool desc = ((i & ksz) == 0);
                    if (desc ? (a < bb2) : (a > bb2)) { list[i] = bb2; list[ixj] = a; }
                }
            }
            __syncthreads();
        }
    }

    if (t < KK) {
        float s = 0.0f; unsigned idx = 0;
        if (t < n) {
            unsigned long long cv = list[t];
            s = __uint_as_float((unsigned)(cv >> 32));
            idx = ~(unsigned)(cv & 0xFFFFFFFFu) & 0x1FFFFFu;
        }
        unsigned sp = idx & (HWs - 1);
        float cls = (float)(idx >> 14);
        float ysf = (float)(sp >> 7);
        float xsf = (float)(sp & 127);
        const float* __restrict__ ob  = offs + (size_t)b * 2 * HWs;
        const float* __restrict__ bbx = bbox + (size_t)b * 2 * HWs;
        float cx = xsf + ob[sp];
        float cy = ysf + ob[HWs + sp];
        float w = bbx[sp];
        float h = bbx[HWs + sp];
        float* row = out + ((size_t)b * KK + t) * 7;
        row[0] = (float)image_id[b];
        row[1] = (cx - w * 0.5f) * 4.0f;
        row[2] = (cy - h * 0.5f) * 4.0f;
        row[3] = (cx + w * 0.5f) * 4.0f;
        row[4] = (cy + h * 0.5f) * 4.0f;
        row[5] = s;
        row[6] = cls;
    }
}

extern "C" void kernel_launch(void* const* d_in, const int* in_sizes, int n_in,
                              void* d_out, int out_size, void* d_ws, size_t ws_size,
                              hipStream_t stream) {
    const float* hm      = (const float*)d_in[0];
    const float* bbox    = (const float*)d_in[1];
    const float* offset  = (const float*)d_in[2];
    const int*   img_id  = (const int*)d_in[3];
    float* out = (float*)d_out;

    char* ws = (char*)d_ws;
    int*      bhist = (int*)(ws + OFF_BHIST);
    int*      pwcnt = (int*)(ws + OFF_PWCNT);
    int*      pscnt = (int*)(ws + OFF_PSCNT);
    unsigned* surv  = (unsigned*)(ws + OFF_SURV);
    unsigned* rec   = (unsigned*)(ws + OFF_REC);

    zero_hist_kernel<<<32, 256, 0, stream>>>((int4*)bhist);
    nms_kernel<<<NBLK, 256, 0, stream>>>(hm, rec, pwcnt);
    hist_kernel<<<BB * 10, 256, 0, stream>>>(rec, pwcnt, bhist);
    filter_kernel<<<NBLK, 256, 0, stream>>>(rec, pwcnt, bhist, surv, pscnt);
    topk_kernel<<<BB, 256, 0, stream>>>(surv, pscnt, hm, bbox, offset, img_id, out);
}

// Round 19
// 65.884 us; speedup vs baseline: 1.4998x; 1.2477x over previous
//
#include <hip/hip_runtime.h>

#define BB 16
#define CC 80
#define HWs 16384           // H*W
#define KK 100
#define NBIN 2048           // histogram bins = okey(logit) >> 21
#define NBLK (BB * CC * 2)  // 2560 half-plane blocks
#define NSLOT 160           // filter slots per batch = CC*2
#define WCAP 288            // records per WAVE slot (mean ~228, +4 sigma)
#define SBCAP 64            // survivors per filter slot (mean ~4)

// ws layout (bytes)
#define OFF_BHIST 0                          // 16*2048*4 = 131072
#define OFF_CUT   131072                     // 64
#define OFF_PWCNT 131136                     // 10240*4 = 40960
#define OFF_PSCNT 172096                     // 2560*4 = 10240
#define OFF_SURV  182336                     // 2560*64*4 = 655360
#define OFF_REC   837696                     // 10240*288*4 = 11796480 (end 12.63MB)

__device__ __forceinline__ unsigned okey(float f) {
    unsigned u = __float_as_uint(f);
    return (u & 0x80000000u) ? ~u : (u | 0x80000000u);
}

// zero bhist (128 KB)
__global__ __launch_bounds__(256) void zero_hist_kernel(int4* __restrict__ bhist) {
    int i = blockIdx.x * 256 + threadIdx.x;          // 8192 int4 total
    if (i < BB * NBIN / 4) bhist[i] = make_int4(0, 0, 0, 0);
}

// One block per half-plane (2560 blocks). ZERO LDS, ZERO atomics, ZERO
// barriers. Each WAVE owns a private record slot; offsets = 6-shfl wave
// scan + popc(mask&(bit-1)); plain stores only. (Verified R18, absmax 0.0.)
__global__ __launch_bounds__(256) void nms_kernel(const float* __restrict__ hm,
                                                  unsigned* __restrict__ rec,
                                                  int* __restrict__ pwcnt) {
    const int blk = blockIdx.x;            // plane*2 + half
    const int plane = blk >> 1;
    const int half = blk & 1;
    const int b = plane / CC;
    const int c = plane - b * CC;
    const int t = threadIdx.x;
    const int lane = t & 63;
    const int wid = t >> 6;
    const int sx = t & 31;                 // 4-wide column strip
    const int x0 = sx << 2;
    const int g = t >> 5;                  // 8 row-groups
    const int yA = (half << 6) + (g << 2); // rows yA..yA+3
    const int yB = yA + 32;                // rows yB..yB+3
    const float4* __restrict__ src4 =
        reinterpret_cast<const float4*>(hm + (size_t)plane * HWs);

    float4 wa[6], wb[6];
#pragma unroll
    for (int i = 0; i < 6; ++i) {
        int ra = yA - 1 + i; ra = ra < 0 ? 0 : (ra > 127 ? 127 : ra);
        int rb = yB - 1 + i; rb = rb < 0 ? 0 : (rb > 127 ? 127 : rb);
        wa[i] = src4[(ra << 5) + sx];
        wb[i] = src4[(rb << 5) + sx];
    }
    __builtin_amdgcn_sched_barrier(0);

    auto hmax3 = [&](const float4& a) -> float4 {
        float vm1 = __shfl_up(a.w, 1, 32);
        float vp4 = __shfl_down(a.x, 1, 32);
        if (sx == 0) vm1 = a.x;            // SAME padding (self-dup neutral)
        if (sx == 31) vp4 = a.w;
        float4 h;
        h.x = fmaxf(fmaxf(vm1, a.x), a.y);
        h.y = fmaxf(fmaxf(a.x, a.y), a.z);
        h.z = fmaxf(fmaxf(a.y, a.z), a.w);
        h.w = fmaxf(fmaxf(a.z, a.w), vp4);
        return h;
    };

    auto mask_of = [&](const float4* w) -> unsigned {
        unsigned pm = 0;
        float4 hm1 = hmax3(w[0]);
        float4 h0  = hmax3(w[1]);
#pragma unroll
        for (int r = 0; r < 4; ++r) {
            float4 hp1 = hmax3(w[r + 2]);
            if (w[r + 1].x >= fmaxf(fmaxf(hm1.x, h0.x), hp1.x)) pm |= 1u << (r * 4 + 0);
            if (w[r + 1].y >= fmaxf(fmaxf(hm1.y, h0.y), hp1.y)) pm |= 1u << (r * 4 + 1);
            if (w[r + 1].z >= fmaxf(fmaxf(hm1.z, h0.z), hp1.z)) pm |= 1u << (r * 4 + 2);
            if (w[r + 1].w >= fmaxf(fmaxf(hm1.w, h0.w), hp1.w)) pm |= 1u << (r * 4 + 3);
            hm1 = h0; h0 = hp1;
        }
        return pm;
    };

    const unsigned pmA = mask_of(wa);
    const unsigned pmB = mask_of(wb);

    int cntA = __popc(pmA), cntB = __popc(pmB);
    int scA = cntA, scB = cntB;
#pragma unroll
    for (int off = 1; off < 64; off <<= 1) {
        int nA = __shfl_up(scA, off, 64);
        int nB = __shfl_up(scB, off, 64);
        if (lane >= off) { scA += nA; scB += nB; }
    }
    const int totalA = __shfl(scA, 63, 64);
    const int totalB = __shfl(scB, 63, 64);
    const int baseA = scA - cntA;
    const int baseB = totalA + scB - cntB;

    unsigned* __restrict__ wr = rec + (size_t)((blk << 2) + wid) * WCAP;

    auto emit = [&](const float4* w, unsigned pm, int base, int y0) {
#pragma unroll
        for (int r = 0; r < 4; ++r) {
#pragma unroll
            for (int j = 0; j < 4; ++j) {
                unsigned bit = 1u << (r * 4 + j);
                if (pm & bit) {
                    float lv = (j == 0) ? w[r + 1].x : (j == 1) ? w[r + 1].y
                             : (j == 2) ? w[r + 1].z : w[r + 1].w;
                    int slot = base + __popc(pm & (bit - 1));
                    unsigned idx = ((unsigned)c << 14)
                                 | ((unsigned)(y0 + r) << 7) | (unsigned)(x0 + j);
                    if (slot < WCAP)
                        wr[slot] = ((okey(lv) >> 21) << 21) | idx;
                }
            }
        }
    };
    emit(wa, pmA, baseA, yA);
    emit(wb, pmB, baseB, yB);

    if (lane == 63) {
        int tot = totalA + totalB;
        pwcnt[(blk << 2) + wid] = tot > WCAP ? WCAP : tot;
    }
}

// One block per half-plane (2560 blocks, FULL parallelism — R18's 160-block
// serial-slot version was the 82us regression): LDS hist over own 4 wave
// slots (~910 L2-resident records), nonzero-bin global atomic flush.
__global__ __launch_bounds__(256) void hist_kernel(const unsigned* __restrict__ rec,
                                                   const int* __restrict__ pwcnt,
                                                   int* __restrict__ bhist) {
    __shared__ int hist[NBIN];             // 8 KB
    const int bx = blockIdx.x;             // half-plane index
    const int b = bx / NSLOT;
    const int t = threadIdx.x;

    for (int i = t; i < NBIN; i += 256) hist[i] = 0;
    __syncthreads();

#pragma unroll
    for (int k = 0; k < 4; ++k) {
        int ws = (bx << 2) + k;
        int n = pwcnt[ws]; if (n > WCAP) n = WCAP;
        const unsigned* __restrict__ rb = rec + (size_t)ws * WCAP;
        for (int i = t; i < n; i += 256) atomicAdd(&hist[rb[i] >> 21], 1);
    }
    __syncthreads();
    for (int i = t; i < NBIN; i += 256) {
        int hv = hist[i];
        if (hv) atomicAdd(&bhist[b * NBIN + i], hv);   // fire-and-forget
    }
}

// One block per batch: cutoff = largest bin with suffix count >= K
// (superset of the exact sigmoid-top-100 incl. tie groups). (Verified R16.)
__global__ __launch_bounds__(256) void cut_kernel(const int* __restrict__ bhist,
                                                  int* __restrict__ cut) {
    __shared__ int csum[256];
    __shared__ int s_cut;
    const int b = blockIdx.x;
    const int t = threadIdx.x;

    int h[8]; int chunk = 0;
#pragma unroll
    for (int j = 0; j < 8; ++j) {
        h[j] = bhist[b * NBIN + (t << 3) + j];
        chunk += h[j];
    }
    csum[t] = chunk;
    if (t == 0) s_cut = 0;
    __syncthreads();
    for (int off = 1; off < 256; off <<= 1) {
        int v = (t + off < 256) ? csum[t + off] : 0;
        __syncthreads();
        csum[t] += v;
        __syncthreads();
    }
    if (csum[0] > KK) {
        int running = (t < 255) ? csum[t + 1] : 0;
        if (csum[t] >= KK && running < KK) {   // exactly one thread
            for (int j = 7; j >= 0; --j) {
                running += h[j];
                if (running >= KK) { s_cut = (t << 3) + j; break; }
            }
        }
    }
    __syncthreads();
    if (t == 0) cut[b] = s_cut;
}

// One block per half-plane: filter own 4 wave slots against cut[b] ->
// deterministic survivor slot (LDS-atomic compaction only). (R16/R18 logic.)
__global__ __launch_bounds__(256) void filter_kernel(const unsigned* __restrict__ rec,
                                                     const int* __restrict__ pwcnt,
                                                     const int* __restrict__ cut,
                                                     unsigned* __restrict__ surv,
                                                     int* __restrict__ pscnt) {
    __shared__ int s_n;
    const int blk = blockIdx.x;            // b*NSLOT + slot
    const int b = blk / NSLOT;
    const int t = threadIdx.x;
    if (t == 0) s_n = 0;
    __syncthreads();

    const unsigned cutb = (unsigned)cut[b];
    unsigned* __restrict__ sb = surv + (size_t)blk * SBCAP;
#pragma unroll
    for (int k = 0; k < 4; ++k) {
        int ws = (blk << 2) + k;
        int n = pwcnt[ws]; if (n > WCAP) n = WCAP;
        const unsigned* __restrict__ rb = rec + (size_t)ws * WCAP;
        for (int i = t; i < n; i += 256) {
            unsigned rv = rb[i];
            if ((rv >> 21) >= cutb) {
                int sl = atomicAdd(&s_n, 1);   // LDS atomic: rare
                if (sl < SBCAP) sb[sl] = rv & 0x1FFFFFu;
            }
        }
    }
    __syncthreads();
    if (t == 0) pscnt[blk] = s_n > SBCAP ? SBCAP : s_n;
}

// One block per batch: gather survivors, exact logit -> sigmoid, sort by
// (sigmoid_bits desc, idx asc) == lax.top_k tie semantics, gather + emit.
__global__ __launch_bounds__(256) void topk_kernel(const unsigned* __restrict__ surv,
                                                   const int* __restrict__ pscnt,
                                                   const float* __restrict__ hm,
                                                   const float* __restrict__ bbox,
                                                   const float* __restrict__ offs,
                                                   const int* __restrict__ image_id,
                                                   float* __restrict__ out) {
    __shared__ int lcnt[NSLOT];
    __shared__ unsigned uidx[2048];            // 8 KB
    __shared__ unsigned long long list[2048];  // 16 KB
    __shared__ int s_n;
    const int b = blockIdx.x;
    const int t = threadIdx.x;
    const float* __restrict__ hb = hm + (size_t)b * CC * HWs;

    if (t < NSLOT) lcnt[t] = pscnt[b * NSLOT + t];
    if (t == 0) s_n = 0;
    __syncthreads();

    for (int s = t; s < NSLOT; s += 256) {
        int cs = lcnt[s]; if (cs > SBCAP) cs = SBCAP;
        if (cs) {
            int base = atomicAdd(&s_n, cs);
            const unsigned* __restrict__ sb = surv + ((size_t)b * NSLOT + s) * SBCAP;
            for (int k = 0; k < cs; ++k)
                if (base + k < 2048) uidx[base + k] = sb[k];
        }
    }
    __syncthreads();
    int n = s_n; if (n > 2048) n = 2048;

    for (int i = t; i < n; i += 256) {
        unsigned idx = uidx[i];
        float lv = hb[idx];
        float s = 1.0f / (1.0f + expf(-lv));
        list[i] = ((unsigned long long)__float_as_uint(s) << 32) | (unsigned)(~idx);
    }
    int P = 128;
    while (P < n) P <<= 1;
    for (int i = n + t; i < P; i += 256) list[i] = 0ull;
    __syncthreads();

    for (int ksz = 2; ksz <= P; ksz <<= 1) {
        for (int j = ksz >> 1; j > 0; j >>= 1) {
            for (int i = t; i < P; i += 256) {
                int ixj = i ^ j;
                if (ixj > i) {
                    unsigned long long a = list[i], bb2 = list[ixj];
                    bool desc = ((i & ksz) == 0);
                    if (desc ? (a < bb2) : (a > bb2)) { list[i] = bb2; list[ixj] = a; }
                }
            }
            __syncthreads();
        }
    }

    if (t < KK) {
        float s = 0.0f; unsigned idx = 0;
        if (t < n) {
            unsigned long long cv = list[t];
            s = __uint_as_float((unsigned)(cv >> 32));
            idx = ~(unsigned)(cv & 0xFFFFFFFFu) & 0x1FFFFFu;
        }
        unsigned sp = idx & (HWs - 1);
        float cls = (float)(idx >> 14);
        float ysf = (float)(sp >> 7);
        float xsf = (float)(sp & 127);
        const float* __restrict__ ob  = offs + (size_t)b * 2 * HWs;
        const float* __restrict__ bbx = bbox + (size_t)b * 2 * HWs;
        float cx = xsf + ob[sp];
        float cy = ysf + ob[HWs + sp];
        float w = bbx[sp];
        float h = bbx[HWs + sp];
        float* row = out + ((size_t)b * KK + t) * 7;
        row[0] = (float)image_id[b];
        row[1] = (cx - w * 0.5f) * 4.0f;
        row[2] = (cy - h * 0.5f) * 4.0f;
        row[3] = (cx + w * 0.5f) * 4.0f;
        row[4] = (cy + h * 0.5f) * 4.0f;
        row[5] = s;
        row[6] = cls;
    }
}

extern "C" void kernel_launch(void* const* d_in, const int* in_sizes, int n_in,
                              void* d_out, int out_size, void* d_ws, size_t ws_size,
                              hipStream_t stream) {
    const float* hm      = (const float*)d_in[0];
    const float* bbox    = (const float*)d_in[1];
    const float* offset  = (const float*)d_in[2];
    const int*   img_id  = (const int*)d_in[3];
    float* out = (float*)d_out;

    char* ws = (char*)d_ws;
    int*      bhist = (int*)(ws + OFF_BHIST);
    int*      cut   = (int*)(ws + OFF_CUT);
    int*      pwcnt = (int*)(ws + OFF_PWCNT);
    int*      pscnt = (int*)(ws + OFF_PSCNT);
    unsigned* surv  = (unsigned*)(ws + OFF_SURV);
    unsigned* rec   = (unsigned*)(ws + OFF_REC);

    zero_hist_kernel<<<32, 256, 0, stream>>>((int4*)bhist);
    nms_kernel<<<NBLK, 256, 0, stream>>>(hm, rec, pwcnt);
    hist_kernel<<<NBLK, 256, 0, stream>>>(rec, pwcnt, bhist);
    cut_kernel<<<BB, 256, 0, stream>>>(bhist, cut);
    filter_kernel<<<NBLK, 256, 0, stream>>>(rec, pwcnt, cut, surv, pscnt);
    topk_kernel<<<BB, 256, 0, stream>>>(surv, pscnt, hm, bbox, offset, img_id, out);
}